// Round 1
// baseline (191.447 us; speedup 1.0000x reference)
//
#include <hip/hip_runtime.h>
#include <hip/hip_bf16.h>
#include <cmath>

// Problem constants
#define S_LEN 2048
#define HIDN  1024
#define NHEAD 16
#define HDIM  64
#define NBAT  2

static constexpr long NA = (long)NBAT * S_LEN * HIDN;  // 4,194,304 hidden elems
static constexpr long NW = (long)HIDN * HIDN;          // 1,048,576 per weight
static constexpr long NM = (long)NBAT * S_LEN * S_LEN; // 8,388,608 mask elems

typedef __attribute__((ext_vector_type(8))) __bf16 bf16x8;
typedef __attribute__((ext_vector_type(4))) float f32x4;

__device__ __forceinline__ unsigned short f2bf(float f) {
  __hip_bfloat16 h = __float2bfloat16(f);
  unsigned short u;
  __builtin_memcpy(&u, &h, 2);
  return u;
}

__device__ __forceinline__ void gload_lds16(const void* g, void* l) {
  __builtin_amdgcn_global_load_lds(
      (const __attribute__((address_space(1))) void*)g,
      (__attribute__((address_space(3))) void*)l, 16, 0, 0);
}

// ---------------- kernel 1: fp32 -> bf16 conversions ----------------
__global__ __launch_bounds__(256) void convert_kernel(
    const float* __restrict__ hs, const float* __restrict__ wq,
    const float* __restrict__ wk, const float* __restrict__ wv,
    const float* __restrict__ mask, __hip_bfloat16* __restrict__ Abf,
    __hip_bfloat16* __restrict__ Wcat, __hip_bfloat16* __restrict__ Mbf) {
  const long tot4 = (NA + 3 * NW + NM) >> 2;
  for (long i4 = (long)blockIdx.x * blockDim.x + threadIdx.x; i4 < tot4;
       i4 += (long)gridDim.x * blockDim.x) {
    long i = i4 << 2;
    const float* s;
    __hip_bfloat16* dq;
    if (i < NA)               { s = hs + i;                dq = Abf + i; }
    else if (i < NA + NW)     { s = wq + (i - NA);         dq = Wcat + (i - NA); }
    else if (i < NA + 2 * NW) { s = wk + (i - NA - NW);    dq = Wcat + (i - NA); }
    else if (i < NA + 3 * NW) { s = wv + (i - NA - 2 * NW);dq = Wcat + (i - NA); }
    else                      { s = mask + (i - NA - 3 * NW); dq = Mbf + (i - NA - 3 * NW); }
    float4 v = *(const float4*)s;
    union { unsigned short u[4]; uint2 p; } o;
    o.u[0] = f2bf(v.x); o.u[1] = f2bf(v.y); o.u[2] = f2bf(v.z); o.u[3] = f2bf(v.w);
    *(uint2*)dq = o.p;
  }
}

// ---------------- kernel 2: QKV GEMM (m97 structure) ----------------
// C[4096][3072] = A[4096][1024] * Bw[3072][1024]^T ; scatter into q/k/v bf16
__global__ __launch_bounds__(256) void qkv_gemm(
    const __hip_bfloat16* __restrict__ A, const __hip_bfloat16* __restrict__ Bw,
    const float* __restrict__ bq, const float* __restrict__ bk,
    const float* __restrict__ bv, __hip_bfloat16* __restrict__ qb,
    __hip_bfloat16* __restrict__ kb, __hip_bfloat16* __restrict__ vb) {
  __shared__ __hip_bfloat16 sA[128 * 32];
  __shared__ __hip_bfloat16 sB[128 * 32];

  int bid = blockIdx.x;
  int cpx = gridDim.x >> 3;                       // 768/8 = 96, bijective
  int wg = (bid & 7) * cpx + (bid >> 3);          // XCD-aware swizzle
  int bm = wg / 24, bn = wg % 24;
  int tid = threadIdx.x, lane = tid & 63, wid = tid >> 6;
  int wr = wid >> 1, wc = wid & 1;
  int lr = lane & 15, hi = lane >> 4;
  int srow = lane >> 2, scol = (lane & 3) * 8;    // staging: row within chunk, k-elems

  f32x4 acc[4][4] = {};

  for (int kt = 0; kt < 32; ++kt) {
    int k0 = kt * 32;
    // stage A,B tiles: 8 chunks of 1KB each, 2 chunks per wave
#pragma unroll
    for (int cc = 0; cc < 2; ++cc) {
      int c = wid * 2 + cc;
      const __hip_bfloat16* ga =
          A + ((size_t)(bm * 128 + c * 16 + srow) * 1024 + k0 + scol);
      gload_lds16(ga, (char*)sA + c * 1024);
      const __hip_bfloat16* gb =
          Bw + ((size_t)(bn * 128 + c * 16 + srow) * 1024 + k0 + scol);
      gload_lds16(gb, (char*)sB + c * 1024);
    }
    __syncthreads();
    bf16x8 af[4], bf[4];
#pragma unroll
    for (int mt = 0; mt < 4; ++mt)
      af[mt] = *(const bf16x8*)((const char*)sA +
                                ((wr * 64 + mt * 16 + lr) * 32 + hi * 8) * 2);
#pragma unroll
    for (int nt = 0; nt < 4; ++nt)
      bf[nt] = *(const bf16x8*)((const char*)sB +
                                ((wc * 64 + nt * 16 + lr) * 32 + hi * 8) * 2);
#pragma unroll
    for (int mt = 0; mt < 4; ++mt)
#pragma unroll
      for (int nt = 0; nt < 4; ++nt)
        acc[mt][nt] =
            __builtin_amdgcn_mfma_f32_16x16x32_bf16(af[mt], bf[nt], acc[mt][nt], 0, 0, 0);
    __syncthreads();
  }

  // epilogue: scatter to q/k/v in [B][NH][S][HD] bf16 layout (+bias)
#pragma unroll
  for (int nt = 0; nt < 4; ++nt) {
    int nb = bn * 128 + wc * 64 + nt * 16;  // wave-uniform
    int t = nb >> 10;
    int rem = nb & 1023;
    int h = rem >> 6, d0 = rem & 63;
    const float* bp = (t == 0) ? bq : (t == 1) ? bk : bv;
    __hip_bfloat16* ob = (t == 0) ? qb : (t == 1) ? kb : vb;
    float bias = bp[rem + lr];
    int d = d0 + lr;
#pragma unroll
    for (int mt = 0; mt < 4; ++mt) {
#pragma unroll
      for (int r = 0; r < 4; ++r) {
        int m = bm * 128 + wr * 64 + mt * 16 + hi * 4 + r;
        int b = m >> 11, s = m & 2047;
        size_t off = (((size_t)(b * NHEAD + h)) * S_LEN + s) * HDIM + d;
        ob[off] = __float2bfloat16(acc[mt][nt][r] + bias);
      }
    }
  }
}

// ---------------- kernel 3: V -> V^T  ([bh][s][d] -> [bh][d][s]) ----------------
__global__ __launch_bounds__(256) void vtrans_kernel(
    const __hip_bfloat16* __restrict__ vb, __hip_bfloat16* __restrict__ vt) {
  __shared__ __hip_bfloat16 tile[64][72];
  int bh = blockIdx.x >> 5;
  int st = blockIdx.x & 31;
  int t = threadIdx.x;
  int r8 = t >> 3, c8 = (t & 7) * 8;
#pragma unroll
  for (int p = 0; p < 2; ++p) {
    int row = p * 32 + r8;  // s-local
    bf16x8 v = *(const bf16x8*)(vb + ((size_t)bh * S_LEN + st * 64 + row) * HDIM + c8);
    *(bf16x8*)&tile[row][c8] = v;
  }
  __syncthreads();
#pragma unroll
  for (int p = 0; p < 2; ++p) {
    int d = p * 32 + r8;
    union { unsigned short u[8]; bf16x8 v; } o;
#pragma unroll
    for (int j = 0; j < 8; ++j) {
      __hip_bfloat16 e = tile[c8 + j][d];
      __builtin_memcpy(&o.u[j], &e, 2);
    }
    *(bf16x8*)(vt + ((size_t)bh * HDIM + d) * S_LEN + st * 64 + c8) = o.v;
  }
}

// ---------------- kernel 4: fused flash attention with struct mask ----------------
// block = (b, h, 128 q rows); 4 waves x 32 q-rows; KV tile = 64
__global__ __launch_bounds__(256) void attn_kernel(
    const __hip_bfloat16* __restrict__ qb, const __hip_bfloat16* __restrict__ kb,
    const __hip_bfloat16* __restrict__ vt, const __hip_bfloat16* __restrict__ Mbf,
    const float* __restrict__ amask, const float* __restrict__ gate,
    float* __restrict__ out) {
  __shared__ __hip_bfloat16 sK[64][72];
  __shared__ __hip_bfloat16 sV[64][72];          // holds V^T tile: [d][k]
  __shared__ __hip_bfloat16 sP[4][32][72];       // per-wave private P tile

  const float LOG2E = 1.44269504088896340736f;
  const float c2 = LOG2E / 8.0f;                 // 1/sqrt(64) * log2(e)

  int bi = blockIdx.x >> 8;
  int qt = (blockIdx.x >> 4) & 15;
  int h = blockIdx.x & 15;
  int bh = bi * NHEAD + h;
  int tid = threadIdx.x, lane = tid & 63, wid = tid >> 6;
  int lr = lane & 15, hi = lane >> 4;
  float g2 = gate[h] * LOG2E;
  int q0 = qt * 128 + wid * 32;

  // Q fragments straight from global (row-major [s][d], 16B/lane)
  bf16x8 qf[2][2];
#pragma unroll
  for (int mt = 0; mt < 2; ++mt)
#pragma unroll
    for (int ks = 0; ks < 2; ++ks)
      qf[mt][ks] = *(const bf16x8*)(qb + ((size_t)bh * S_LEN + q0 + mt * 16 + lr) * HDIM +
                                    ks * 32 + hi * 8);

  f32x4 O[2][4] = {};
  float mrow[2][4], lrow[2][4];
#pragma unroll
  for (int mt = 0; mt < 2; ++mt)
#pragma unroll
    for (int r = 0; r < 4; ++r) { mrow[mt][r] = -INFINITY; lrow[mt][r] = 0.f; }

  int r8 = tid >> 3, c8 = (tid & 7) * 8;

  for (int kt = 0; kt < 32; ++kt) {
    int k0 = kt * 64;
    __syncthreads();  // previous iter's reads done before overwrite
#pragma unroll
    for (int p = 0; p < 2; ++p) {
      int row = p * 32 + r8;
      bf16x8 kv = *(const bf16x8*)(kb + ((size_t)bh * S_LEN + k0 + row) * HDIM + c8);
      *(bf16x8*)&sK[row][c8] = kv;
      bf16x8 vv = *(const bf16x8*)(vt + ((size_t)bh * HDIM + row) * S_LEN + k0 + c8);
      *(bf16x8*)&sV[row][c8] = vv;
    }
    __syncthreads();

    // ---- QK^T ----
    f32x4 S[2][4] = {};
#pragma unroll
    for (int ks = 0; ks < 2; ++ks) {
      bf16x8 kf[4];
#pragma unroll
      for (int nt = 0; nt < 4; ++nt)
        kf[nt] = *(const bf16x8*)&sK[nt * 16 + lr][ks * 32 + hi * 8];
#pragma unroll
      for (int mt = 0; mt < 2; ++mt)
#pragma unroll
        for (int nt = 0; nt < 4; ++nt)
          S[mt][nt] = __builtin_amdgcn_mfma_f32_16x16x32_bf16(qf[mt][ks], kf[nt],
                                                              S[mt][nt], 0, 0, 0);
    }

    // ---- scores -> exp2 domain with masks ----
    float am[4];
#pragma unroll
    for (int nt = 0; nt < 4; ++nt)
      am[nt] = amask[bi * S_LEN + k0 + nt * 16 + lr] * LOG2E;

#pragma unroll
    for (int mt = 0; mt < 2; ++mt) {
#pragma unroll
      for (int r = 0; r < 4; ++r) {
        int q = q0 + mt * 16 + hi * 4 + r;
        const __hip_bfloat16* mp = Mbf + ((size_t)bi * S_LEN + q) * S_LEN + k0;
#pragma unroll
        for (int nt = 0; nt < 4; ++nt) {
          float mv = __bfloat162float(mp[nt * 16 + lr]);
          S[mt][nt][r] = S[mt][nt][r] * c2 + mv * g2 + am[nt];
        }
        // row max across 64 keys: in-lane over nt, then across 16-lane group
        float rm = fmaxf(fmaxf(S[mt][0][r], S[mt][1][r]), fmaxf(S[mt][2][r], S[mt][3][r]));
#pragma unroll
        for (int sft = 1; sft < 16; sft <<= 1) rm = fmaxf(rm, __shfl_xor(rm, sft, 64));
        float mnew = fmaxf(mrow[mt][r], rm);
        float alpha = exp2f(mrow[mt][r] - mnew);
        mrow[mt][r] = mnew;
        float rs = 0.f;
#pragma unroll
        for (int nt = 0; nt < 4; ++nt) {
          float pv = exp2f(S[mt][nt][r] - mnew);
          S[mt][nt][r] = pv;
          rs += pv;
        }
#pragma unroll
        for (int sft = 1; sft < 16; sft <<= 1) rs += __shfl_xor(rs, sft, 64);
        lrow[mt][r] = lrow[mt][r] * alpha + rs;
#pragma unroll
        for (int dt = 0; dt < 4; ++dt) O[mt][dt][r] *= alpha;
        // P -> wave-private LDS (bf16)
#pragma unroll
        for (int nt = 0; nt < 4; ++nt)
          sP[wid][mt * 16 + hi * 4 + r][nt * 16 + lr] = __float2bfloat16(S[mt][nt][r]);
      }
    }

    // ---- PV ----
#pragma unroll
    for (int ks = 0; ks < 2; ++ks) {
      bf16x8 vf[4], pf[2];
#pragma unroll
      for (int dt = 0; dt < 4; ++dt)
        vf[dt] = *(const bf16x8*)&sV[dt * 16 + lr][ks * 32 + hi * 8];
#pragma unroll
      for (int mt = 0; mt < 2; ++mt)
        pf[mt] = *(const bf16x8*)&sP[wid][mt * 16 + lr][ks * 32 + hi * 8];
#pragma unroll
      for (int mt = 0; mt < 2; ++mt)
#pragma unroll
        for (int dt = 0; dt < 4; ++dt)
          O[mt][dt] = __builtin_amdgcn_mfma_f32_16x16x32_bf16(pf[mt], vf[dt], O[mt][dt], 0, 0, 0);
    }
  }

  // ---- epilogue: normalize + write fp32 ctx [B][S][HID] ----
#pragma unroll
  for (int mt = 0; mt < 2; ++mt) {
#pragma unroll
    for (int r = 0; r < 4; ++r) {
      float inv = 1.0f / lrow[mt][r];
      int q = q0 + mt * 16 + hi * 4 + r;
#pragma unroll
      for (int dt = 0; dt < 4; ++dt) {
        int d = dt * 16 + lr;
        out[((size_t)bi * S_LEN + q) * HIDN + h * HDIM + d] = O[mt][dt][r] * inv;
      }
    }
  }
}

extern "C" void kernel_launch(void* const* d_in, const int* in_sizes, int n_in,
                              void* d_out, int out_size, void* d_ws, size_t ws_size,
                              hipStream_t stream) {
  const float* hs    = (const float*)d_in[0];
  const float* amask = (const float*)d_in[1];
  const float* smask = (const float*)d_in[2];
  const float* Wq    = (const float*)d_in[3];
  const float* bq    = (const float*)d_in[4];
  const float* Wk    = (const float*)d_in[5];
  const float* bk    = (const float*)d_in[6];
  const float* Wv    = (const float*)d_in[7];
  const float* bv    = (const float*)d_in[8];
  const float* gate  = (const float*)d_in[9];

  char* ws = (char*)d_ws;
  // layout (bytes): Abf 8MiB | Wcat 6MiB | qb 8MiB | kb 8MiB | vb 8MiB | Mbf 16MiB
  __hip_bfloat16* Abf  = (__hip_bfloat16*)(ws);
  __hip_bfloat16* Wcat = (__hip_bfloat16*)(ws + 8388608);
  __hip_bfloat16* qb   = (__hip_bfloat16*)(ws + 8388608 + 6291456);
  __hip_bfloat16* kb   = qb + NA;
  __hip_bfloat16* vb   = kb + NA;
  __hip_bfloat16* Mbf  = vb + NA;
  __hip_bfloat16* vt   = Abf;  // alias: Abf dead after qkv_gemm

  convert_kernel<<<2048, 256, 0, stream>>>(hs, Wq, Wk, Wv, smask, Abf, Wcat, Mbf);
  qkv_gemm<<<768, 256, 0, stream>>>(Abf, Wcat, bq, bk, bv, qb, kb, vb);
  vtrans_kernel<<<1024, 256, 0, stream>>>(vb, vt);
  attn_kernel<<<512, 256, 0, stream>>>(qb, kb, vt, Mbf, amask, gate, (float*)d_out);
}

// Round 2
// 174.044 us; speedup vs baseline: 1.1000x; 1.1000x over previous
//
#include <hip/hip_runtime.h>
#include <hip/hip_bf16.h>
#include <cmath>

// Problem constants
#define S_LEN 2048
#define HIDN  1024
#define NHEAD 16
#define HDIM  64
#define NBAT  2

static constexpr long NA = (long)NBAT * S_LEN * HIDN;  // 4,194,304 hidden elems
static constexpr long NW = (long)HIDN * HIDN;          // 1,048,576 per weight
static constexpr long NM = (long)NBAT * S_LEN * S_LEN; // 8,388,608 mask elems

typedef __attribute__((ext_vector_type(8))) __bf16 bf16x8;
typedef __attribute__((ext_vector_type(4))) float f32x4;
typedef __attribute__((ext_vector_type(16))) float f32x16;
typedef __attribute__((ext_vector_type(4))) unsigned short u16x4;

__device__ __forceinline__ unsigned short f2bf(float f) {
  __hip_bfloat16 h = __float2bfloat16(f);
  unsigned short u;
  __builtin_memcpy(&u, &h, 2);
  return u;
}

__device__ __forceinline__ float bfu2f(unsigned short u) {
  unsigned v = (unsigned)u << 16;
  float f;
  __builtin_memcpy(&f, &v, 4);
  return f;
}

__device__ __forceinline__ unsigned pkbf(float a, float b) {
  return ((unsigned)f2bf(b) << 16) | (unsigned)f2bf(a);
}

__device__ __forceinline__ void gload_lds16(const void* g, void* l) {
  __builtin_amdgcn_global_load_lds(
      (const __attribute__((address_space(1))) void*)g,
      (__attribute__((address_space(3))) void*)l, 16, 0, 0);
}

// ---------------- kernel 1: fp32 -> bf16 conversions ----------------
__global__ __launch_bounds__(256) void convert_kernel(
    const float* __restrict__ hs, const float* __restrict__ wq,
    const float* __restrict__ wk, const float* __restrict__ wv,
    const float* __restrict__ mask, __hip_bfloat16* __restrict__ Abf,
    __hip_bfloat16* __restrict__ Wcat, __hip_bfloat16* __restrict__ Mbf) {
  const long tot4 = (NA + 3 * NW + NM) >> 2;
  for (long i4 = (long)blockIdx.x * blockDim.x + threadIdx.x; i4 < tot4;
       i4 += (long)gridDim.x * blockDim.x) {
    long i = i4 << 2;
    const float* s;
    __hip_bfloat16* dq;
    if (i < NA)               { s = hs + i;                dq = Abf + i; }
    else if (i < NA + NW)     { s = wq + (i - NA);         dq = Wcat + (i - NA); }
    else if (i < NA + 2 * NW) { s = wk + (i - NA - NW);    dq = Wcat + (i - NA); }
    else if (i < NA + 3 * NW) { s = wv + (i - NA - 2 * NW);dq = Wcat + (i - NA); }
    else                      { s = mask + (i - NA - 3 * NW); dq = Mbf + (i - NA - 3 * NW); }
    float4 v = *(const float4*)s;
    union { unsigned short u[4]; uint2 p; } o;
    o.u[0] = f2bf(v.x); o.u[1] = f2bf(v.y); o.u[2] = f2bf(v.z); o.u[3] = f2bf(v.w);
    *(uint2*)dq = o.p;
  }
}

// ---------------- kernel 2: QKV GEMM (m97 structure) ----------------
__global__ __launch_bounds__(256) void qkv_gemm(
    const __hip_bfloat16* __restrict__ A, const __hip_bfloat16* __restrict__ Bw,
    const float* __restrict__ bq, const float* __restrict__ bk,
    const float* __restrict__ bv, __hip_bfloat16* __restrict__ qb,
    __hip_bfloat16* __restrict__ kb, __hip_bfloat16* __restrict__ vb) {
  __shared__ __hip_bfloat16 sA[128 * 32];
  __shared__ __hip_bfloat16 sB[128 * 32];

  int bid = blockIdx.x;
  int cpx = gridDim.x >> 3;
  int wg = (bid & 7) * cpx + (bid >> 3);
  int bm = wg / 24, bn = wg % 24;
  int tid = threadIdx.x, lane = tid & 63, wid = tid >> 6;
  int wr = wid >> 1, wc = wid & 1;
  int lr = lane & 15, hi = lane >> 4;
  int srow = lane >> 2, scol = (lane & 3) * 8;

  f32x4 acc[4][4] = {};

  for (int kt = 0; kt < 32; ++kt) {
    int k0 = kt * 32;
#pragma unroll
    for (int cc = 0; cc < 2; ++cc) {
      int c = wid * 2 + cc;
      const __hip_bfloat16* ga =
          A + ((size_t)(bm * 128 + c * 16 + srow) * 1024 + k0 + scol);
      gload_lds16(ga, (char*)sA + c * 1024);
      const __hip_bfloat16* gb =
          Bw + ((size_t)(bn * 128 + c * 16 + srow) * 1024 + k0 + scol);
      gload_lds16(gb, (char*)sB + c * 1024);
    }
    __syncthreads();
    bf16x8 af[4], bf[4];
#pragma unroll
    for (int mt = 0; mt < 4; ++mt)
      af[mt] = *(const bf16x8*)((const char*)sA +
                                ((wr * 64 + mt * 16 + lr) * 32 + hi * 8) * 2);
#pragma unroll
    for (int nt = 0; nt < 4; ++nt)
      bf[nt] = *(const bf16x8*)((const char*)sB +
                                ((wc * 64 + nt * 16 + lr) * 32 + hi * 8) * 2);
#pragma unroll
    for (int mt = 0; mt < 4; ++mt)
#pragma unroll
      for (int nt = 0; nt < 4; ++nt)
        acc[mt][nt] =
            __builtin_amdgcn_mfma_f32_16x16x32_bf16(af[mt], bf[nt], acc[mt][nt], 0, 0, 0);
    __syncthreads();
  }

#pragma unroll
  for (int nt = 0; nt < 4; ++nt) {
    int nb = bn * 128 + wc * 64 + nt * 16;
    int t = nb >> 10;
    int rem = nb & 1023;
    int h = rem >> 6, d0 = rem & 63;
    const float* bp = (t == 0) ? bq : (t == 1) ? bk : bv;
    __hip_bfloat16* ob = (t == 0) ? qb : (t == 1) ? kb : vb;
    float bias = bp[rem + lr];
    int d = d0 + lr;
#pragma unroll
    for (int mt = 0; mt < 4; ++mt) {
#pragma unroll
      for (int r = 0; r < 4; ++r) {
        int m = bm * 128 + wr * 64 + mt * 16 + hi * 4 + r;
        int b = m >> 11, s = m & 2047;
        size_t off = (((size_t)(b * NHEAD + h)) * S_LEN + s) * HDIM + d;
        ob[off] = __float2bfloat16(acc[mt][nt][r] + bias);
      }
    }
  }
}

// ---------------- kernel 3: V -> V^T  ([bh][s][d] -> [bh][d][s]) ----------------
__global__ __launch_bounds__(256) void vtrans_kernel(
    const __hip_bfloat16* __restrict__ vb, __hip_bfloat16* __restrict__ vt) {
  __shared__ __hip_bfloat16 tile[64][72];
  int bh = blockIdx.x >> 5;
  int st = blockIdx.x & 31;
  int t = threadIdx.x;
  int r8 = t >> 3, c8 = (t & 7) * 8;
#pragma unroll
  for (int p = 0; p < 2; ++p) {
    int row = p * 32 + r8;
    bf16x8 v = *(const bf16x8*)(vb + ((size_t)bh * S_LEN + st * 64 + row) * HDIM + c8);
    *(bf16x8*)&tile[row][c8] = v;
  }
  __syncthreads();
#pragma unroll
  for (int p = 0; p < 2; ++p) {
    int d = p * 32 + r8;
    union { unsigned short u[8]; bf16x8 v; } o;
#pragma unroll
    for (int j = 0; j < 8; ++j) {
      __hip_bfloat16 e = tile[c8 + j][d];
      __builtin_memcpy(&o.u[j], &e, 2);
    }
    *(bf16x8*)(vt + ((size_t)bh * HDIM + d) * S_LEN + st * 64 + c8) = o.v;
  }
}

// ---------------- kernel 4: fused flash attention, swapped-QK^T form ----------------
// block = (b, qtile of 128, h); 4 waves x 32 q-rows; KV tile = 64
// S^T = K*Q^T via mfma_32x32x16 -> lane owns q = lane&31 (stats lane-local)
// O^T = V^T * P^T -> col = q = lane&31 (rescale lane-local)
__global__ __launch_bounds__(256) void attn_kernel(
    const __hip_bfloat16* __restrict__ qb, const __hip_bfloat16* __restrict__ kbuf,
    const __hip_bfloat16* __restrict__ vt, const __hip_bfloat16* __restrict__ Mbf,
    const float* __restrict__ amask, const float* __restrict__ gate,
    float* __restrict__ out) {
  __shared__ alignas(16) char sK[2][8192];   // K tile [64 k][128B], XOR-swizzled
  __shared__ alignas(16) char sVT[2][8192];  // V^T tile [64 d][128B], XOR-swizzled
  __shared__ alignas(16) float sAm[2048];    // amask row * LOG2E

  const float LOG2E = 1.44269504088896340736f;
  const float c2 = LOG2E / 8.0f;  // 1/sqrt(64) * log2(e)

  int bi = blockIdx.x >> 8;
  int qt = (blockIdx.x >> 4) & 15;
  int h = blockIdx.x & 15;
  int bh = bi * NHEAD + h;
  int tid = threadIdx.x, lane = tid & 63, wid = tid >> 6;
  int l31 = lane & 31, hi2 = lane >> 5;
  int qrow = qt * 128 + wid * 32 + l31;
  float g2 = gate[h] * LOG2E;

  // amask -> LDS (pre-scaled by log2e)
  for (int i = tid; i < 512; i += 256) {
    float4 a = ((const float4*)(amask + (size_t)bi * S_LEN))[i];
    a.x *= LOG2E; a.y *= LOG2E; a.z *= LOG2E; a.w *= LOG2E;
    ((float4*)sAm)[i] = a;
  }

  // Q fragments: Q[q=l31][d], 4 chunks of 8 consecutive d at hi2*8
  bf16x8 qf[4];
  {
    const __hip_bfloat16* qp = qb + ((size_t)bh * S_LEN + qrow) * HDIM + hi2 * 8;
#pragma unroll
    for (int dc = 0; dc < 4; ++dc) qf[dc] = *(const bf16x8*)(qp + dc * 16);
  }

  int r8 = lane >> 3, col16 = lane & 7;
  int swzc = (col16 ^ r8) << 4;  // pre-swizzled source column (16B units)

  // stage KV tile kt into buffer buf (4 x global_load_lds per wave)
  auto stage = [&](int buf, int kt) {
    int k0 = kt * 64;
#pragma unroll
    for (int cc = 0; cc < 2; ++cc) {
      int ch = wid * 2 + cc;
      int row = ch * 8 + r8;
      const char* gk = (const char*)kbuf +
                       ((size_t)bh * S_LEN + k0 + row) * 128 + swzc;
      gload_lds16(gk, &sK[buf][ch * 1024]);
      const char* gv = (const char*)vt + ((size_t)bh * HDIM + row) * 4096 +
                       (size_t)k0 * 2 + swzc;
      gload_lds16(gv, &sVT[buf][ch * 1024]);
    }
  };

  f32x16 O[2] = {};
  float m = -INFINITY, l = 0.f;
  int rswz = (l31 & 7) << 4;

  stage(0, 0);
  __syncthreads();  // drains stage(0) + amask writes

  for (int kt = 0; kt < 32; ++kt) {
    int cur = kt & 1;
    if (kt < 31) stage(cur ^ 1, kt + 1);  // overlaps with compute below
    int k0 = kt * 64;

    // ---- S^T = K * Q^T ----
    f32x16 st[2] = {};
#pragma unroll
    for (int kb = 0; kb < 2; ++kb) {
      int row = kb * 32 + l31;
#pragma unroll
      for (int dc = 0; dc < 4; ++dc) {
        bf16x8 kf = *(const bf16x8*)(&sK[cur][row * 128 + ((dc * 32 + hi2 * 16) ^ rswz)]);
        st[kb] = __builtin_amdgcn_mfma_f32_32x32x16_bf16(kf, qf[dc], st[kb], 0, 0, 0);
      }
    }

    // ---- masks + online softmax (all lane-local for q = l31) ----
    const unsigned short* mrow =
        (const unsigned short*)Mbf + ((size_t)bi * S_LEN + qrow) * S_LEN + k0 + hi2 * 4;
    float pmax = -3.4e38f;
#pragma unroll
    for (int kb = 0; kb < 2; ++kb) {
#pragma unroll
      for (int rp = 0; rp < 4; ++rp) {
        union { u16x4 v; unsigned short e[4]; } mv;
        mv.v = *(const u16x4*)(mrow + kb * 32 + rp * 8);
        float4 am = *(const float4*)(sAm + k0 + kb * 32 + rp * 8 + hi2 * 4);
        float a[4] = {am.x, am.y, am.z, am.w};
#pragma unroll
        for (int rr = 0; rr < 4; ++rr) {
          float s = fmaf(st[kb][rp * 4 + rr], c2, fmaf(bfu2f(mv.e[rr]), g2, a[rr]));
          st[kb][rp * 4 + rr] = s;
          pmax = fmaxf(pmax, s);
        }
      }
    }
    pmax = fmaxf(pmax, __shfl_xor(pmax, 32));
    if (__any(pmax > m + 8.f)) {  // defer-max (T13)
      float mnew = fmaxf(m, pmax);
      float alpha = exp2f(m - mnew);
      m = mnew;
      l *= alpha;
      O[0] *= alpha;
      O[1] *= alpha;
    }
    float rs = 0.f;
#pragma unroll
    for (int kb = 0; kb < 2; ++kb)
#pragma unroll
      for (int reg = 0; reg < 16; ++reg) {
        float pv = exp2f(st[kb][reg] - m);
        st[kb][reg] = pv;
        rs += pv;
      }
    rs += __shfl_xor(rs, 32);
    l += rs;

    // ---- pack P to bf16 pairs; lane holds k = kb*32 + rr + 8*rp + 4*hi2 ----
    unsigned pk[2][4][2];
#pragma unroll
    for (int kb = 0; kb < 2; ++kb)
#pragma unroll
      for (int rp = 0; rp < 4; ++rp) {
        pk[kb][rp][0] = pkbf(st[kb][rp * 4 + 0], st[kb][rp * 4 + 1]);
        pk[kb][rp][1] = pkbf(st[kb][rp * 4 + 2], st[kb][rp * 4 + 3]);
      }

    // ---- PV: O^T += V^T * P^T ----
#pragma unroll
    for (int ks = 0; ks < 4; ++ks) {
      int kbb = ks >> 1, rp = (ks & 1) * 2;
      unsigned a0 = pk[kbb][rp][0], a1 = pk[kbb][rp][1];
      unsigned b0 = pk[kbb][rp + 1][0], b1 = pk[kbb][rp + 1][1];
      unsigned sa0 = __shfl_xor(a0, 32), sa1 = __shfl_xor(a1, 32);
      unsigned sb0 = __shfl_xor(b0, 32), sb1 = __shfl_xor(b1, 32);
      union { unsigned w[4]; bf16x8 v; } B;
      B.w[0] = hi2 ? sb0 : a0;
      B.w[1] = hi2 ? sb1 : a1;
      B.w[2] = hi2 ? b0 : sa0;
      B.w[3] = hi2 ? b1 : sa1;
#pragma unroll
      for (int dt = 0; dt < 2; ++dt) {
        int row = dt * 32 + l31;
        bf16x8 vf = *(const bf16x8*)(&sVT[cur][row * 128 + ((ks * 32 + hi2 * 16) ^ rswz)]);
        O[dt] = __builtin_amdgcn_mfma_f32_32x32x16_bf16(vf, B.v, O[dt], 0, 0, 0);
      }
    }
    __syncthreads();  // readers done before next overwrite; drains next stage
  }

  // ---- epilogue: lane-local normalize, scatter stores ----
  float inv = 1.0f / l;
  float* orow = out + ((size_t)bi * S_LEN + qrow) * HIDN + h * HDIM;
#pragma unroll
  for (int dt = 0; dt < 2; ++dt)
#pragma unroll
    for (int reg = 0; reg < 16; ++reg)
      orow[dt * 32 + (reg & 3) + 8 * (reg >> 2) + 4 * hi2] = O[dt][reg] * inv;
}

extern "C" void kernel_launch(void* const* d_in, const int* in_sizes, int n_in,
                              void* d_out, int out_size, void* d_ws, size_t ws_size,
                              hipStream_t stream) {
  const float* hs    = (const float*)d_in[0];
  const float* amask = (const float*)d_in[1];
  const float* smask = (const float*)d_in[2];
  const float* Wq    = (const float*)d_in[3];
  const float* bq    = (const float*)d_in[4];
  const float* Wk    = (const float*)d_in[5];
  const float* bk    = (const float*)d_in[6];
  const float* Wv    = (const float*)d_in[7];
  const float* bv    = (const float*)d_in[8];
  const float* gate  = (const float*)d_in[9];

  char* ws = (char*)d_ws;
  __hip_bfloat16* Abf  = (__hip_bfloat16*)(ws);
  __hip_bfloat16* Wcat = (__hip_bfloat16*)(ws + 8388608);
  __hip_bfloat16* qb   = (__hip_bfloat16*)(ws + 8388608 + 6291456);
  __hip_bfloat16* kb   = qb + NA;
  __hip_bfloat16* vb   = kb + NA;
  __hip_bfloat16* Mbf  = vb + NA;
  __hip_bfloat16* vt   = Abf;  // alias: Abf dead after qkv_gemm

  convert_kernel<<<2048, 256, 0, stream>>>(hs, Wq, Wk, Wv, smask, Abf, Wcat, Mbf);
  qkv_gemm<<<768, 256, 0, stream>>>(Abf, Wcat, bq, bk, bv, qb, kb, vb);
  vtrans_kernel<<<1024, 256, 0, stream>>>(vb, vt);
  attn_kernel<<<512, 256, 0, stream>>>(qb, kb, vt, Mbf, amask, gate, (float*)d_out);
}